// Round 3
// baseline (32.507 us; speedup 1.0000x reference)
//
#include <hip/hip_runtime.h>

#define NN    1024
#define IN_D  256
#define OUT_D 256
#define BN    4     // n-rows per block; grid = NN/BN = 256 blocks = 1/CU

typedef float v2f __attribute__((ext_vector_type(2)));

// Optional ws usage (gated on ws_size): v2f wlr[i*OUT+o] = {w_l, w_r}  (512 KB)
#define WLR_BYTES (sizeof(v2f) * IN_D * OUT_D)

__global__ __launch_bounds__(256) void fz_prep(
    const float* __restrict__ wb, const float* __restrict__ wa,
    const float* __restrict__ wc, v2f* __restrict__ wlr) {
    int t = blockIdx.x * 256 + threadIdx.x;        // 0 .. IN*OUT-1
    float b = wb[t];
    float a = fmaxf(wa[t], 0.0f);                  // relu(w_a)
    float c = fmaxf(wc[t], 0.0f);                  // relu(w_c)
    v2f w; w.x = b - a; w.y = b + c;               // {w_l, w_r}
    wlr[t] = w;
}

template <bool PREP>
__global__ __launch_bounds__(256) void fz_main(
    const float* __restrict__ hl, const float* __restrict__ hr,
    const float* __restrict__ wb, const float* __restrict__ wa,
    const float* __restrict__ wc, const v2f* __restrict__ wlr,
    const float* __restrict__ bb, const float* __restrict__ ba,
    const float* __restrict__ bc, float* __restrict__ out) {
    __shared__ __align__(16) v2f ab[BN][IN_D];     // 8 KB: {hl, hr} pairs

    const int o  = threadIdx.x;                    // output column, 0..255
    const int n0 = blockIdx.x * BN;                // first n-row of this block

    // stage BN rows of hl/hr into LDS (coalesced f32 loads)
    for (int p = threadIdx.x; p < BN * IN_D; p += 256) {
        int tn = p >> 8;                           // p / IN_D
        int ii = p & (IN_D - 1);                   // p % IN_D
        v2f v; v.x = hl[(n0 + tn) * IN_D + ii];
        v.y = hr[(n0 + tn) * IN_D + ii];
        ab[tn][ii] = v;
    }
    __syncthreads();

    v2f slr[BN];                                   // {sum_l, sum_r} per row
#pragma unroll
    for (int t = 0; t < BN; ++t) { slr[t].x = 0.0f; slr[t].y = 0.0f; }

#pragma unroll 8
    for (int ii = 0; ii < IN_D; ++ii) {
        float wl, wr;
        if (PREP) {
            v2f w = wlr[ii * OUT_D + o];           // 8B/lane, coalesced, L2-resident
            wl = w.x; wr = w.y;
        } else {
            int wi = ii * OUT_D + o;
            wl = wb[wi] - fmaxf(wa[wi], 0.0f);
            wr = wb[wi] + fmaxf(wc[wi], 0.0f);
        }
        v2f wl2; wl2.x = wl; wl2.y = wl;
        v2f wr2; wr2.x = wr; wr2.y = wr;
#pragma unroll
        for (int t = 0; t < BN; ++t) {
            v2f a2  = ab[t][ii];                   // LDS broadcast (conflict-free)
            v2f q13 = a2 * wl2;                    // {a*wl, b*wl}  -> v_pk_mul_f32
            v2f q24 = a2 * wr2;                    // {a*wr, b*wr}  -> v_pk_mul_f32
            // data invariants: hr >= hl (b>=a) and wr > 0
            //   => min(p1..p4) = min3(a*wl, b*wl, a*wr)
            //   => max(p1..p4) = max3(a*wl, b*wl, b*wr)
            float mn = fminf(fminf(q13.x, q13.y), q24.x);   // v_min3_f32
            float mx = fmaxf(fmaxf(q13.x, q13.y), q24.y);   // v_max3_f32
            v2f mm; mm.x = mn; mm.y = mx;
            slr[t] += mm;                          // v_pk_add_f32 (or 2 adds)
        }
    }

    // fused bias + f32 store
    float bv = bb[o];
    float bl = bv - fmaxf(ba[o], 0.0f);
    float br = bv + fmaxf(bc[o], 0.0f);
#pragma unroll
    for (int t = 0; t < BN; ++t) {
        out[(n0 + t) * OUT_D + o]              = slr[t].x + bl;
        out[NN * OUT_D + (n0 + t) * OUT_D + o] = slr[t].y + br;
    }
}

extern "C" void kernel_launch(void* const* d_in, const int* in_sizes, int n_in,
                              void* d_out, int out_size, void* d_ws, size_t ws_size,
                              hipStream_t stream) {
    const float* hl = (const float*)d_in[0];
    const float* hr = (const float*)d_in[1];
    const float* wb = (const float*)d_in[2];
    const float* wa = (const float*)d_in[3];
    const float* wc = (const float*)d_in[4];
    const float* bb = (const float*)d_in[5];
    const float* ba = (const float*)d_in[6];
    const float* bc = (const float*)d_in[7];
    float* out = (float*)d_out;

    dim3 grid(NN / BN);

    if (ws_size >= WLR_BYTES) {
        v2f* wlr = (v2f*)d_ws;
        fz_prep<<<(IN_D * OUT_D) / 256, 256, 0, stream>>>(wb, wa, wc, wlr);
        fz_main<true><<<grid, 256, 0, stream>>>(hl, hr, wb, wa, wc, wlr,
                                                bb, ba, bc, out);
    } else {
        fz_main<false><<<grid, 256, 0, stream>>>(hl, hr, wb, wa, wc, nullptr,
                                                 bb, ba, bc, out);
    }
}

// Round 4
// 25.739 us; speedup vs baseline: 1.2629x; 1.2629x over previous
//
#include <hip/hip_runtime.h>

#define NN    1024
#define IN_D  256
#define OUT_D 256
#define BN    4              // n-rows per block
#define NI2   (IN_D / 2)     // 128 packed ii-pairs
#define KH2   (NI2 / 2)      // 64 ii-pairs per K-half

typedef float v2f __attribute__((ext_vector_type(2)));
typedef float v4f __attribute__((ext_vector_type(4)));

// ws: float4 wlr2[ii2*OUT+o] = {wl(2*ii2,o), wr(2*ii2,o), wl(2*ii2+1,o), wr(2*ii2+1,o)}
#define WLR_BYTES (sizeof(float4) * NI2 * OUT_D)   // 512 KB

__global__ __launch_bounds__(256) void fz_prep(
    const float* __restrict__ wb, const float* __restrict__ wa,
    const float* __restrict__ wc, float4* __restrict__ wlr2) {
    int t = blockIdx.x * 256 + threadIdx.x;        // 0 .. NI2*OUT-1
    int ii2 = t >> 8;
    int o   = t & (OUT_D - 1);
    int i0  = (2 * ii2) * OUT_D + o;
    int i1  = i0 + OUT_D;
    float4 w;
    w.x = wb[i0] - fmaxf(wa[i0], 0.0f);
    w.y = wb[i0] + fmaxf(wc[i0], 0.0f);
    w.z = wb[i1] - fmaxf(wa[i1], 0.0f);
    w.w = wb[i1] + fmaxf(wc[i1], 0.0f);
    wlr2[t] = w;
}

template <bool PREP>
__global__ __launch_bounds__(512) void fz_main(
    const float* __restrict__ hl, const float* __restrict__ hr,
    const float* __restrict__ wb, const float* __restrict__ wa,
    const float* __restrict__ wc, const float4* __restrict__ wlr2,
    const float* __restrict__ bb, const float* __restrict__ ba,
    const float* __restrict__ bc, float* __restrict__ out) {
    __shared__ __align__(16) v2f ab[BN][IN_D];     // 8 KB: {hl, hr} f32 pairs
    __shared__ __align__(16) v2f pl[BN][OUT_D];    // 8 KB: h=1 partials

    const int o  = threadIdx.x & (OUT_D - 1);      // output column
    const int h  = threadIdx.x >> 8;               // K-half: 0 or 1
    const int n0 = blockIdx.x * BN;

    // stage BN rows of {hl,hr} (coalesced f32 loads; 1024 pairs / 512 thr)
    for (int p = threadIdx.x; p < BN * IN_D; p += 512) {
        int tn = p >> 8;
        int ii = p & (IN_D - 1);
        v2f v; v.x = hl[(n0 + tn) * IN_D + ii];
        v.y = hr[(n0 + tn) * IN_D + ii];
        ab[tn][ii] = v;
    }
    __syncthreads();

    v2f slr[BN];
#pragma unroll
    for (int t = 0; t < BN; ++t) { slr[t].x = 0.0f; slr[t].y = 0.0f; }

    const float4* wp = wlr2 + (size_t)(h * KH2) * OUT_D + o;

#pragma unroll 4
    for (int j = 0; j < KH2; ++j) {                // 64 ii-pairs per half
        float4 w;
        if (PREP) {
            w = wp[(size_t)j * OUT_D];             // 16B/lane, coalesced, L2-resident
        } else {
            int i0 = (h * KH2 + j) * 2 * OUT_D + o;
            int i1 = i0 + OUT_D;
            w.x = wb[i0] - fmaxf(wa[i0], 0.0f);
            w.y = wb[i0] + fmaxf(wc[i0], 0.0f);
            w.z = wb[i1] - fmaxf(wa[i1], 0.0f);
            w.w = wb[i1] + fmaxf(wc[i1], 0.0f);
        }
        const int ii = (h * KH2 + j) * 2;
#pragma unroll
        for (int t = 0; t < BN; ++t) {
            v4f a4 = *reinterpret_cast<const v4f*>(&ab[t][ii]);  // ds_read_b128 broadcast
            // ii+0: a=a4.x b=a4.y, wl=w.x wr=w.y
            v2f ab0; ab0.x = a4.x; ab0.y = a4.y;
            v2f l0 = ab0 * w.x;                    // {a*wl, b*wl}  v_pk_mul_f32
            v2f r0 = ab0 * w.y;                    // {a*wr, b*wr}
            // invariants: b>=a, wr>0 => min=min3(awl,bwl,awr), max=max3(awl,bwl,bwr)
            v2f mm0;
            mm0.x = fminf(fminf(l0.x, l0.y), r0.x);   // v_min3_f32
            mm0.y = fmaxf(fmaxf(l0.x, l0.y), r0.y);   // v_max3_f32
            slr[t] += mm0;                             // v_pk_add_f32
            // ii+1: a=a4.z b=a4.w, wl=w.z wr=w.w
            v2f ab1; ab1.x = a4.z; ab1.y = a4.w;
            v2f l1 = ab1 * w.z;
            v2f r1 = ab1 * w.w;
            v2f mm1;
            mm1.x = fminf(fminf(l1.x, l1.y), r1.x);
            mm1.y = fmaxf(fmaxf(l1.x, l1.y), r1.y);
            slr[t] += mm1;
        }
    }

    if (h == 1) {
#pragma unroll
        for (int t = 0; t < BN; ++t) pl[t][o] = slr[t];
    }
    __syncthreads();
    if (h == 0) {
        float bv = bb[o];
        float bl = bv - fmaxf(ba[o], 0.0f);
        float br = bv + fmaxf(bc[o], 0.0f);
#pragma unroll
        for (int t = 0; t < BN; ++t) {
            v2f s = slr[t];
            v2f q = pl[t][o];                      // 8B/lane: 2-way aliasing = free
            out[(n0 + t) * OUT_D + o]              = s.x + q.x + bl;
            out[NN * OUT_D + (n0 + t) * OUT_D + o] = s.y + q.y + br;
        }
    }
}

extern "C" void kernel_launch(void* const* d_in, const int* in_sizes, int n_in,
                              void* d_out, int out_size, void* d_ws, size_t ws_size,
                              hipStream_t stream) {
    const float* hl = (const float*)d_in[0];
    const float* hr = (const float*)d_in[1];
    const float* wb = (const float*)d_in[2];
    const float* wa = (const float*)d_in[3];
    const float* wc = (const float*)d_in[4];
    const float* bb = (const float*)d_in[5];
    const float* ba = (const float*)d_in[6];
    const float* bc = (const float*)d_in[7];
    float* out = (float*)d_out;

    dim3 grid(NN / BN);

    if (ws_size >= WLR_BYTES) {
        float4* wlr2 = (float4*)d_ws;
        fz_prep<<<(NI2 * OUT_D) / 256, 256, 0, stream>>>(wb, wa, wc, wlr2);
        fz_main<true><<<grid, 512, 0, stream>>>(hl, hr, wb, wa, wc, wlr2,
                                                bb, ba, bc, out);
    } else {
        fz_main<false><<<grid, 512, 0, stream>>>(hl, hr, wb, wa, wc, nullptr,
                                                 bb, ba, bc, out);
    }
}

// Round 5
// 25.542 us; speedup vs baseline: 1.2727x; 1.0077x over previous
//
#include <hip/hip_runtime.h>

#define NN     1024
#define IN_D   256
#define OUT_D  256
#define BN     4               // n-rows per block; grid = 256 = 1 block/CU
#define NI2    (IN_D / 2)      // 128 packed ii-pairs
#define NG     8               // K-groups (tid>>7), 32 i's each
#define JPG    (NI2 / NG)      // 16 ii-pairs per group
#define OSLOTS (OUT_D / 2)     // 128; each thread owns o = oslot and oslot+128

typedef float v2f __attribute__((ext_vector_type(2)));
typedef float v4f __attribute__((ext_vector_type(4)));

// ws: float4 wlr2[ii2*OUT+o] = {wl(2ii2,o), wr(2ii2,o), wl(2ii2+1,o), wr(2ii2+1,o)}
#define WLR_BYTES (sizeof(float4) * NI2 * OUT_D)   // 512 KB

__global__ __launch_bounds__(256) void fz_prep(
    const float* __restrict__ wb, const float* __restrict__ wa,
    const float* __restrict__ wc, float4* __restrict__ wlr2) {
    int t = blockIdx.x * 256 + threadIdx.x;        // 0 .. NI2*OUT-1
    int ii2 = t >> 8;
    int o   = t & (OUT_D - 1);
    int i0  = (2 * ii2) * OUT_D + o;
    int i1  = i0 + OUT_D;
    float4 w;
    w.x = wb[i0] - fmaxf(wa[i0], 0.0f);
    w.y = wb[i0] + fmaxf(wc[i0], 0.0f);
    w.z = wb[i1] - fmaxf(wa[i1], 0.0f);
    w.w = wb[i1] + fmaxf(wc[i1], 0.0f);
    wlr2[t] = w;
}

template <bool PREP>
__global__ __launch_bounds__(1024) void fz_main(
    const float* __restrict__ hl, const float* __restrict__ hr,
    const float* __restrict__ wb, const float* __restrict__ wa,
    const float* __restrict__ wc, const float4* __restrict__ wlr2,
    const float* __restrict__ bb, const float* __restrict__ ba,
    const float* __restrict__ bc, float* __restrict__ out) {
    __shared__ __align__(16) v2f ab[BN][IN_D];               // 8 KB {hl,hr}
    __shared__ __align__(16) v2f pl[NG - 1][BN][2][OSLOTS];  // 56 KB partials

    const int tid   = threadIdx.x;
    const int oslot = tid & (OSLOTS - 1);          // o0 = oslot, o1 = oslot+128
    const int g     = tid >> 7;                    // K-group 0..7
    const int n0    = blockIdx.x * BN;

    // stage BN rows of {hl,hr}: exactly one (row, ii) per thread, coalesced
    {
        int row = tid >> 8;
        int ii  = tid & (IN_D - 1);
        v2f v; v.x = hl[(n0 + row) * IN_D + ii];
        v.y = hr[(n0 + row) * IN_D + ii];
        ab[row][ii] = v;
    }
    __syncthreads();

    v2f acc[BN][2];
#pragma unroll
    for (int t = 0; t < BN; ++t) {
        acc[t][0].x = 0.0f; acc[t][0].y = 0.0f;
        acc[t][1].x = 0.0f; acc[t][1].y = 0.0f;
    }

    const int j0 = g * JPG;
    const float4* wp0 = wlr2 + (size_t)j0 * OUT_D + oslot;
    const float4* wp1 = wp0 + OSLOTS;

#pragma unroll 4
    for (int j = 0; j < JPG; ++j) {
        float4 w0, w1;
        if (PREP) {
            w0 = wp0[(size_t)j * OUT_D];           // 16B/lane, coalesced
            w1 = wp1[(size_t)j * OUT_D];
        } else {
            int base = (j0 + j) * 2 * OUT_D;
            int i00 = base + oslot, i01 = i00 + OUT_D;
            w0.x = wb[i00] - fmaxf(wa[i00], 0.0f);
            w0.y = wb[i00] + fmaxf(wc[i00], 0.0f);
            w0.z = wb[i01] - fmaxf(wa[i01], 0.0f);
            w0.w = wb[i01] + fmaxf(wc[i01], 0.0f);
            int i10 = base + oslot + OSLOTS, i11 = i10 + OUT_D;
            w1.x = wb[i10] - fmaxf(wa[i10], 0.0f);
            w1.y = wb[i10] + fmaxf(wc[i10], 0.0f);
            w1.z = wb[i11] - fmaxf(wa[i11], 0.0f);
            w1.w = wb[i11] + fmaxf(wc[i11], 0.0f);
        }
        const int ii = (j0 + j) * 2;
#pragma unroll
        for (int t = 0; t < BN; ++t) {
            v4f a4 = *reinterpret_cast<const v4f*>(&ab[t][ii]);  // broadcast b128
            v2f p0; p0.x = a4.x; p0.y = a4.y;      // {a,b} for ii
            v2f p1; p1.x = a4.z; p1.y = a4.w;      // {a,b} for ii+1
            // invariants: b>=a, wr>0 => min=min3(awl,bwl,awr), max=max3(awl,bwl,bwr)
            {   // o0, ii
                v2f l = p0 * w0.x, r = p0 * w0.y;  // v_pk_mul_f32
                v2f mm; mm.x = fminf(fminf(l.x, l.y), r.x);
                mm.y = fmaxf(fmaxf(l.x, l.y), r.y);
                acc[t][0] += mm;
            }
            {   // o0, ii+1
                v2f l = p1 * w0.z, r = p1 * w0.w;
                v2f mm; mm.x = fminf(fminf(l.x, l.y), r.x);
                mm.y = fmaxf(fmaxf(l.x, l.y), r.y);
                acc[t][0] += mm;
            }
            {   // o1, ii
                v2f l = p0 * w1.x, r = p0 * w1.y;
                v2f mm; mm.x = fminf(fminf(l.x, l.y), r.x);
                mm.y = fmaxf(fmaxf(l.x, l.y), r.y);
                acc[t][1] += mm;
            }
            {   // o1, ii+1
                v2f l = p1 * w1.z, r = p1 * w1.w;
                v2f mm; mm.x = fminf(fminf(l.x, l.y), r.x);
                mm.y = fmaxf(fmaxf(l.x, l.y), r.y);
                acc[t][1] += mm;
            }
        }
    }

    if (g > 0) {
#pragma unroll
        for (int t = 0; t < BN; ++t) {
            pl[g - 1][t][0][oslot] = acc[t][0];    // 8B stride: 2-way = free
            pl[g - 1][t][1][oslot] = acc[t][1];
        }
    }
    __syncthreads();
    if (g == 0) {
        const int o0 = oslot, o1 = oslot + OSLOTS;
        float bl0 = bb[o0] - fmaxf(ba[o0], 0.0f);
        float br0 = bb[o0] + fmaxf(bc[o0], 0.0f);
        float bl1 = bb[o1] - fmaxf(ba[o1], 0.0f);
        float br1 = bb[o1] + fmaxf(bc[o1], 0.0f);
#pragma unroll
        for (int t = 0; t < BN; ++t) {
            v2f s0 = acc[t][0], s1 = acc[t][1];
#pragma unroll
            for (int gg = 0; gg < NG - 1; ++gg) {
                s0 += pl[gg][t][0][oslot];
                s1 += pl[gg][t][1][oslot];
            }
            size_t rl = (size_t)(n0 + t) * OUT_D;
            size_t rr = (size_t)NN * OUT_D + rl;
            out[rl + o0] = s0.x + bl0;
            out[rr + o0] = s0.y + br0;
            out[rl + o1] = s1.x + bl1;
            out[rr + o1] = s1.y + br1;
        }
    }
}

extern "C" void kernel_launch(void* const* d_in, const int* in_sizes, int n_in,
                              void* d_out, int out_size, void* d_ws, size_t ws_size,
                              hipStream_t stream) {
    const float* hl = (const float*)d_in[0];
    const float* hr = (const float*)d_in[1];
    const float* wb = (const float*)d_in[2];
    const float* wa = (const float*)d_in[3];
    const float* wc = (const float*)d_in[4];
    const float* bb = (const float*)d_in[5];
    const float* ba = (const float*)d_in[6];
    const float* bc = (const float*)d_in[7];
    float* out = (float*)d_out;

    dim3 grid(NN / BN);

    if (ws_size >= WLR_BYTES) {
        float4* wlr2 = (float4*)d_ws;
        fz_prep<<<(NI2 * OUT_D) / 256, 256, 0, stream>>>(wb, wa, wc, wlr2);
        fz_main<true><<<grid, 1024, 0, stream>>>(hl, hr, wb, wa, wc, wlr2,
                                                 bb, ba, bc, out);
    } else {
        fz_main<false><<<grid, 1024, 0, stream>>>(hl, hr, wb, wa, wc, nullptr,
                                                  bb, ba, bc, out);
    }
}